// Round 6
// baseline (616.152 us; speedup 1.0000x reference)
//
#include <hip/hip_runtime.h>
#include <math.h>

// Round 6: flash attention pipelined (K double-buffered, V+K(next) DMA issued
// before S/softmax so the barrier drain is overlapped; exp2 softmax).
// fc/fc2 GEMMs moved to 256x128 tile (512 thr, 8 waves) for higher arithmetic
// intensity per staged byte. qkv/proj stay on the 128x128 kernel.
//
// ws: [0,16M) lnbuf | [16,48M) qk | [48,64M) vT | [64,80M) ybuf
//     [80,144M) h | [144,170M) wT

#define M_ROWS 8192
#define T_SEQ 2048
#define N_EMB 1024
#define N_HEADS 16
#define HEAD_D 64

typedef _Float16 f16;
typedef __attribute__((ext_vector_type(8))) _Float16 f16x8;
typedef __attribute__((ext_vector_type(4))) _Float16 f16x4;
typedef __attribute__((ext_vector_type(4))) float f32x4;

__device__ __forceinline__ void async16(void* lds, const void* g) {
    __builtin_amdgcn_global_load_lds(
        (const __attribute__((address_space(1))) unsigned int*)g,
        (__attribute__((address_space(3))) unsigned int*)lds, 16, 0, 0);
}

__device__ __forceinline__ float gelu_tanh(float v) {
    float u = 0.7978845608028654f * (v + 0.044715f * v * v * v);
    float e = __expf(2.0f * u);
    float t = 1.0f - 2.0f / (e + 1.0f);
    return 0.5f * v * (1.0f + t);
}

// ---------------------------------------------------------------- weight convert
__launch_bounds__(256)
__global__ void wconv_kernel(const float* __restrict__ W, f16* __restrict__ WT,
                             int K, int N) {
    __shared__ float t[32][33];
    int tx = threadIdx.x & 31, ty = threadIdx.x >> 5;
    int n0 = blockIdx.x * 32, k0 = blockIdx.y * 32;
    #pragma unroll
    for (int r = 0; r < 4; r++)
        t[ty * 4 + r][tx] = W[(size_t)(k0 + ty * 4 + r) * N + n0 + tx];
    __syncthreads();
    #pragma unroll
    for (int r = 0; r < 4; r++)
        WT[(size_t)(n0 + ty * 4 + r) * K + k0 + tx] = (f16)t[tx][ty * 4 + r];
}

// ---------------------------------------------------------------- LayerNorm -> f16
__launch_bounds__(256)
__global__ void ln_kernel(const float* __restrict__ x, const float* __restrict__ g,
                          const float* __restrict__ b, f16* __restrict__ y) {
    int row = blockIdx.x;
    int tid = threadIdx.x;
    const float* xr = x + (size_t)row * N_EMB;
    float4 v = *(const float4*)(xr + tid * 4);
    float s  = v.x + v.y + v.z + v.w;
    float sq = v.x * v.x + v.y * v.y + v.z * v.z + v.w * v.w;
    #pragma unroll
    for (int off = 32; off > 0; off >>= 1) {
        s  += __shfl_down(s, off);
        sq += __shfl_down(sq, off);
    }
    __shared__ float ws_[4], wq_[4];
    __shared__ float mean_s, rstd_s;
    int lane = tid & 63, wid = tid >> 6;
    if (lane == 0) { ws_[wid] = s; wq_[wid] = sq; }
    __syncthreads();
    if (tid == 0) {
        float st = ws_[0] + ws_[1] + ws_[2] + ws_[3];
        float qt = wq_[0] + wq_[1] + wq_[2] + wq_[3];
        float mu = st * (1.0f / N_EMB);
        float var = qt * (1.0f / N_EMB) - mu * mu;
        mean_s = mu;
        rstd_s = rsqrtf(var + 1e-5f);
    }
    __syncthreads();
    float mu = mean_s, r = rstd_s;
    float4 gv = *(const float4*)(g + tid * 4);
    float4 bv = *(const float4*)(b + tid * 4);
    f16x4 o;
    o.x = (f16)((v.x - mu) * r * gv.x + bv.x);
    o.y = (f16)((v.y - mu) * r * gv.y + bv.y);
    o.z = (f16)((v.z - mu) * r * gv.z + bv.z);
    o.w = (f16)((v.w - mu) * r * gv.w + bv.w);
    *(f16x4*)(y + (size_t)row * N_EMB + tid * 4) = o;
}

// ---------------------------------------------------------------- GEMM 128x128
// (round-5 kernel, unchanged; used for qkv and proj)
template <int EPI>
__launch_bounds__(256)
__global__ void gemm_f16(const f16* __restrict__ A, const f16* __restrict__ Bt,
                         const float* __restrict__ bias, const float* __restrict__ res,
                         float* __restrict__ Cf, f16* __restrict__ Ch,
                         f16* __restrict__ vT, int K, int N) {
    __shared__ f16 As[2][128 * 32];
    __shared__ f16 Bs[2][128 * 32];
    int tid = threadIdx.x;
    int lane = tid & 63, wave = tid >> 6;
    int wr = wave >> 1, wc = wave & 1;
    int quad = lane >> 4, l16 = lane & 15;
    int m0 = blockIdx.y * 128, n0 = blockIdx.x * 128;

    int r0 = tid >> 2;
    int s0 = (tid & 3) * 8;
    const f16* paA0 = A  + (size_t)(m0 + r0) * K + s0;
    const f16* paA1 = A  + (size_t)(m0 + r0 + 64) * K + s0;
    const f16* paB0 = Bt + (size_t)(n0 + r0) * K + s0;
    const f16* paB1 = Bt + (size_t)(n0 + r0 + 64) * K + s0;
    char* dA0 = (char*)As + (size_t)tid * 16;
    char* dA1 = (char*)As + (size_t)(256 + tid) * 16;
    char* dB0 = (char*)Bs + (size_t)tid * 16;
    char* dB1 = (char*)Bs + (size_t)(256 + tid) * 16;

    async16(dA0, paA0);
    async16(dA1, paA1);
    async16(dB0, paB0);
    async16(dB1, paB1);

    f32x4 acc[4][4] = {};
    int p = 0;
    for (int k0 = 0; k0 < K; k0 += 32, p ^= 1) {
        __syncthreads();
        if (k0 + 32 < K) {
            int koff = k0 + 32;
            async16(dA0 + (p ^ 1) * 8192, paA0 + koff);
            async16(dA1 + (p ^ 1) * 8192, paA1 + koff);
            async16(dB0 + (p ^ 1) * 8192, paB0 + koff);
            async16(dB1 + (p ^ 1) * 8192, paB1 + koff);
        }
        const f16* as = As[p];
        const f16* bs = Bs[p];
        f16x8 af[4], bf[4];
        #pragma unroll
        for (int i = 0; i < 4; i++)
            af[i] = *(const f16x8*)&as[(wr * 64 + i * 16 + l16) * 32 + quad * 8];
        #pragma unroll
        for (int j = 0; j < 4; j++)
            bf[j] = *(const f16x8*)&bs[(wc * 64 + j * 16 + l16) * 32 + quad * 8];
        #pragma unroll
        for (int i = 0; i < 4; i++)
            #pragma unroll
            for (int j = 0; j < 4; j++)
                acc[i][j] = __builtin_amdgcn_mfma_f32_16x16x32_f16(
                    af[i], bf[j], acc[i][j], 0, 0, 0);
    }

    #pragma unroll
    for (int i = 0; i < 4; i++) {
        int row0 = m0 + wr * 64 + i * 16 + quad * 4;
        #pragma unroll
        for (int j = 0; j < 4; j++) {
            int col = n0 + wc * 64 + j * 16 + l16;
            float bb = bias[col];
            if (EPI == 3) {
                if (n0 < 2048) {
                    #pragma unroll
                    for (int r = 0; r < 4; r++)
                        Ch[(size_t)(row0 + r) * 2048 + col] = (f16)(acc[i][j][r] + bb);
                } else {
                    int hh = (col - 2048) >> 6, dd = col & 63;
                    int bb_ = row0 >> 11, t0 = row0 & 2047;
                    f16x4 pk;
                    pk.x = (f16)(acc[i][j][0] + bb);
                    pk.y = (f16)(acc[i][j][1] + bb);
                    pk.z = (f16)(acc[i][j][2] + bb);
                    pk.w = (f16)(acc[i][j][3] + bb);
                    *(f16x4*)(vT + ((size_t)(bb_ * 16 + hh) * 64 + dd) * 2048 + t0) = pk;
                }
            } else {
                #pragma unroll
                for (int r = 0; r < 4; r++) {
                    size_t idx = (size_t)(row0 + r) * N + col;
                    float v = acc[i][j][r] + bb;
                    if (EPI == 1) v += res[idx];
                    if (EPI == 2) Ch[idx] = (f16)gelu_tanh(v);
                    else          Cf[idx] = v;
                }
            }
        }
    }
}

// ---------------------------------------------------------------- GEMM 256x128
// 512 thr = 8 waves (4x2 of 64x64). Same dbuf single-barrier K-loop.
// Higher MACs-per-staged-byte (42.7 vs 32) and 3 staging insts/thread (vs 4).
template <int EPI>
__launch_bounds__(512)
__global__ void gemm_f16_big(const f16* __restrict__ A, const f16* __restrict__ Bt,
                             const float* __restrict__ bias, const float* __restrict__ res,
                             float* __restrict__ Cf, f16* __restrict__ Ch,
                             int K, int N) {
    __shared__ f16 As[2][256 * 32];
    __shared__ f16 Bs[2][128 * 32];
    int tid = threadIdx.x;
    int lane = tid & 63, wave = tid >> 6;      // 0..7
    int wr = wave >> 1, wc = wave & 1;         // wr 0..3, wc 0..1
    int quad = lane >> 4, l16 = lane & 15;
    int m0 = blockIdx.y * 256, n0 = blockIdx.x * 128;

    int r0 = tid >> 2;                         // 0..127
    int s0 = (tid & 3) * 8;
    const f16* paA0 = A  + (size_t)(m0 + r0) * K + s0;
    const f16* paA1 = A  + (size_t)(m0 + r0 + 128) * K + s0;
    const f16* paB0 = Bt + (size_t)(n0 + r0) * K + s0;
    char* dA0 = (char*)As + (size_t)tid * 16;
    char* dA1 = (char*)As + (size_t)(512 + tid) * 16;
    char* dB0 = (char*)Bs + (size_t)tid * 16;

    async16(dA0, paA0);
    async16(dA1, paA1);
    async16(dB0, paB0);

    f32x4 acc[4][4] = {};
    int p = 0;
    for (int k0 = 0; k0 < K; k0 += 32, p ^= 1) {
        __syncthreads();
        if (k0 + 32 < K) {
            int koff = k0 + 32;
            async16(dA0 + (p ^ 1) * 16384, paA0 + koff);
            async16(dA1 + (p ^ 1) * 16384, paA1 + koff);
            async16(dB0 + (p ^ 1) * 8192,  paB0 + koff);
        }
        const f16* as = As[p];
        const f16* bs = Bs[p];
        f16x8 af[4], bf[4];
        #pragma unroll
        for (int i = 0; i < 4; i++)
            af[i] = *(const f16x8*)&as[(wr * 64 + i * 16 + l16) * 32 + quad * 8];
        #pragma unroll
        for (int j = 0; j < 4; j++)
            bf[j] = *(const f16x8*)&bs[(wc * 64 + j * 16 + l16) * 32 + quad * 8];
        #pragma unroll
        for (int i = 0; i < 4; i++)
            #pragma unroll
            for (int j = 0; j < 4; j++)
                acc[i][j] = __builtin_amdgcn_mfma_f32_16x16x32_f16(
                    af[i], bf[j], acc[i][j], 0, 0, 0);
    }

    #pragma unroll
    for (int i = 0; i < 4; i++) {
        int row0 = m0 + wr * 64 + i * 16 + quad * 4;
        #pragma unroll
        for (int j = 0; j < 4; j++) {
            int col = n0 + wc * 64 + j * 16 + l16;
            float bb = bias[col];
            #pragma unroll
            for (int r = 0; r < 4; r++) {
                size_t idx = (size_t)(row0 + r) * N + col;
                float v = acc[i][j][r] + bb;
                if (EPI == 1) v += res[idx];
                if (EPI == 2) Ch[idx] = (f16)gelu_tanh(v);
                else          Cf[idx] = v;
            }
        }
    }
}

// ---------------------------------------------------------------- MFMA flash
// Pipelined: K double-buffered; per iter barrier A drains K(t) (in flight one
// full iter), then V(t)+K(t+1) DMAs issue and overlap S+softmax before
// barrier B. P goes through per-wave LDS in two 64-j halves (Ps 32x72).
// Softmax in exp2 form: Q pre-scaled by 0.125*log2(e).
__launch_bounds__(256, 2)
__global__ void flash_kernel(const f16* __restrict__ qk, const f16* __restrict__ vT,
                             f16* __restrict__ y) {
    __shared__ __align__(16) char smem[67584];
    f16* Ks0 = (f16*)smem;                     // K buf0 [128 j][8 g of 8 d], g^=(j&7)
    f16* Ks1 = (f16*)(smem + 16384);           // K buf1
    f16* Vs  = (f16*)(smem + 32768);           // [64 d][16 g of 8 j], g^=(d&7)
    int tid = threadIdx.x;
    int lane = tid & 63, w = tid >> 6;
    int quad = lane >> 4, l16 = lane & 15;
    f16* Ps = (f16*)(smem + 49152 + w * 4608); // per-wave [32 q][72], one 64-j half

    int qt = 15 - blockIdx.x;                  // long blocks first
    int bh = blockIdx.y;
    int b = bh >> 4, h = bh & 15;
    int q0 = qt * 128;
    const size_t qkrow = (size_t)b * T_SEQ * 2048;

    // Q B-frags, pre-scaled by 0.125*log2(e) (exp2 softmax)
    const f16 qsc = (f16)0.1803368801f;
    f16x8 qf[2][2];
    #pragma unroll
    for (int qn = 0; qn < 2; qn++) {
        int q = q0 + w * 32 + qn * 16 + l16;
        #pragma unroll
        for (int dblk = 0; dblk < 2; dblk++) {
            f16x8 t = *(const f16x8*)(qk + qkrow + (size_t)q * 2048 +
                                      h * 64 + dblk * 32 + quad * 8);
            #pragma unroll
            for (int e = 0; e < 8; e++) t[e] = t[e] * qsc;
            qf[qn][dblk] = t;
        }
    }

    // staging slots (lane-constant)
    int kj = tid >> 1;                          // rows j covered: kj, kj+128? no:
    // K tile: 1024 segs / 4 insts of 256 -> L = i*256+tid
    // V tile: same
    // (keep round-5 indexing, computed inline)

    // prologue: stage K(0) into Ks0
    {
        #pragma unroll
        for (int i = 0; i < 4; i++) {
            int L = i * 256 + tid;
            int j = L >> 3, g1 = L & 7;
            int g = g1 ^ (j & 7);
            async16((char*)Ks0 + (size_t)L * 16,
                    qk + qkrow + (size_t)j * 2048 + 1024 + h * 64 + g * 8);
        }
    }

    float m_r[2] = {-INFINITY, -INFINITY};
    float l_r[2] = {0.0f, 0.0f};
    f32x4 Oacc[2][4] = {};

    int p = 0;
    for (int jt = 0; jt <= qt; jt++, p ^= 1) {
        int j0 = jt * 128;
        __syncthreads();   // drains K(jt) DMA; Vs/Ks[p^1] free of readers

        // issue V(jt) and K(jt+1) — overlap with S+softmax below
        #pragma unroll
        for (int i = 0; i < 4; i++) {
            int L = i * 256 + tid;
            int d = L >> 4, g1 = L & 15;
            int g = (g1 & 8) | ((g1 ^ d) & 7);
            async16((char*)Vs + (size_t)L * 16,
                    vT + ((size_t)bh * 64 + d) * 2048 + j0 + g * 8);
        }
        if (jt < qt) {
            char* knext = (char*)(p ? Ks0 : Ks1);
            int jn0 = j0 + 128;
            #pragma unroll
            for (int i = 0; i < 4; i++) {
                int L = i * 256 + tid;
                int j = L >> 3, g1 = L & 7;
                int g = g1 ^ (j & 7);
                async16(knext + (size_t)L * 16,
                        qk + qkrow + (size_t)(jn0 + j) * 2048 + 1024 + h * 64 + g * 8);
            }
        }

        // S^T = K . Q^T from resident K buffer
        const f16* kbuf = p ? Ks1 : Ks0;
        f32x4 S[8][2];
        #pragma unroll
        for (int jm = 0; jm < 8; jm++) {
            f16x8 kf[2];
            #pragma unroll
            for (int dblk = 0; dblk < 2; dblk++) {
                int j = jm * 16 + l16;
                int g = (dblk * 4 + quad) ^ (j & 7);
                kf[dblk] = *(const f16x8*)(kbuf + (size_t)(j * 8 + g) * 8);
            }
            #pragma unroll
            for (int qn = 0; qn < 2; qn++) {
                f32x4 s = {};
                s = __builtin_amdgcn_mfma_f32_16x16x32_f16(kf[0], qf[qn][0], s, 0, 0, 0);
                s = __builtin_amdgcn_mfma_f32_16x16x32_f16(kf[1], qf[qn][1], s, 0, 0, 0);
                S[jm][qn] = s;
            }
        }

        if (jt == qt) {
            #pragma unroll
            for (int jm = 0; jm < 8; jm++)
                #pragma unroll
                for (int qn = 0; qn < 2; qn++)
                    #pragma unroll
                    for (int r = 0; r < 4; r++) {
                        int jl = jm * 16 + quad * 4 + r;
                        int ql = w * 32 + qn * 16 + l16;
                        if (jl > ql) S[jm][qn][r] = -1e30f;
                    }
        }

        // online softmax, exp2 form
        float alpha[2];
        #pragma unroll
        for (int qn = 0; qn < 2; qn++) {
            float tmax = -INFINITY;
            #pragma unroll
            for (int jm = 0; jm < 8; jm++)
                #pragma unroll
                for (int r = 0; r < 4; r++)
                    tmax = fmaxf(tmax, S[jm][qn][r]);
            tmax = fmaxf(tmax, __shfl_xor(tmax, 16));
            tmax = fmaxf(tmax, __shfl_xor(tmax, 32));
            float mnew = fmaxf(m_r[qn], tmax);
            alpha[qn] = exp2f(m_r[qn] - mnew);
            m_r[qn] = mnew;
            float rsum = 0.0f;
            #pragma unroll
            for (int jm = 0; jm < 8; jm++)
                #pragma unroll
                for (int r = 0; r < 4; r++) {
                    float pp = exp2f(S[jm][qn][r] - mnew);
                    S[jm][qn][r] = pp;
                    rsum += pp;
                }
            rsum += __shfl_xor(rsum, 16);
            rsum += __shfl_xor(rsum, 32);
            l_r[qn] = l_r[qn] * alpha[qn] + rsum;
        }

        // rescale O by alpha
        float aPV[2][4];
        #pragma unroll
        for (int m = 0; m < 2; m++)
            #pragma unroll
            for (int r = 0; r < 4; r++)
                aPV[m][r] = __shfl(alpha[m], quad * 20 + r);
        #pragma unroll
        for (int m = 0; m < 2; m++)
            #pragma unroll
            for (int n = 0; n < 4; n++)
                #pragma unroll
                for (int r = 0; r < 4; r++)
                    Oacc[m][n][r] *= aPV[m][r];

        // write P half 0 (j 0..63) before barrier B (per-wave private)
        #pragma unroll
        for (int jm = 0; jm < 4; jm++)
            #pragma unroll
            for (int qn = 0; qn < 2; qn++) {
                f16x4 pk;
                pk.x = (f16)S[jm][qn][0];
                pk.y = (f16)S[jm][qn][1];
                pk.z = (f16)S[jm][qn][2];
                pk.w = (f16)S[jm][qn][3];
                *(f16x4*)(Ps + (size_t)(qn * 16 + l16) * 72 + jm * 16 + quad * 4) = pk;
            }

        __syncthreads();   // drains V(jt) (+K(jt+1)); Vs ready

        // PV halves: kblk 0,1 from P-half0; then write half1; kblk 2,3
        #pragma unroll
        for (int kblk = 0; kblk < 2; kblk++) {
            f16x8 pf[2];
            #pragma unroll
            for (int m = 0; m < 2; m++)
                pf[m] = *(const f16x8*)(Ps + (size_t)(m * 16 + l16) * 72 +
                                        kblk * 32 + quad * 8);
            f16x8 vf[4];
            #pragma unroll
            for (int n = 0; n < 4; n++) {
                int d = n * 16 + l16;
                int g = kblk * 4 + quad;
                int gs = (g & 8) | ((g ^ d) & 7);
                vf[n] = *(const f16x8*)(Vs + (size_t)(d * 16 + gs) * 8);
            }
            #pragma unroll
            for (int m = 0; m < 2; m++)
                #pragma unroll
                for (int n = 0; n < 4; n++)
                    Oacc[m][n] = __builtin_amdgcn_mfma_f32_16x16x32_f16(
                        pf[m], vf[n], Oacc[m][n], 0, 0, 0);
        }
        #pragma unroll
        for (int jm = 4; jm < 8; jm++)
            #pragma unroll
            for (int qn = 0; qn < 2; qn++) {
                f16x4 pk;
                pk.x = (f16)S[jm][qn][0];
                pk.y = (f16)S[jm][qn][1];
                pk.z = (f16)S[jm][qn][2];
                pk.w = (f16)S[jm][qn][3];
                *(f16x4*)(Ps + (size_t)(qn * 16 + l16) * 72 + (jm - 4) * 16 + quad * 4) = pk;
            }
        #pragma unroll
        for (int kblk = 2; kblk < 4; kblk++) {
            f16x8 pf[2];
            #pragma unroll
            for (int m = 0; m < 2; m++)
                pf[m] = *(const f16x8*)(Ps + (size_t)(m * 16 + l16) * 72 +
                                        (kblk - 2) * 32 + quad * 8);
            f16x8 vf[4];
            #pragma unroll
            for (int n = 0; n < 4; n++) {
                int d = n * 16 + l16;
                int g = kblk * 4 + quad;
                int gs = (g & 8) | ((g ^ d) & 7);
                vf[n] = *(const f16x8*)(Vs + (size_t)(d * 16 + gs) * 8);
            }
            #pragma unroll
            for (int m = 0; m < 2; m++)
                #pragma unroll
                for (int n = 0; n < 4; n++)
                    Oacc[m][n] = __builtin_amdgcn_mfma_f32_16x16x32_f16(
                        pf[m], vf[n], Oacc[m][n], 0, 0, 0);
        }
    }

    #pragma unroll
    for (int m = 0; m < 2; m++) {
        float lPV[4];
        #pragma unroll
        for (int r = 0; r < 4; r++)
            lPV[r] = 1.0f / __shfl(l_r[m], quad * 20 + r);
        #pragma unroll
        for (int n = 0; n < 4; n++) {
            #pragma unroll
            for (int r = 0; r < 4; r++) {
                int q = q0 + w * 32 + m * 16 + quad * 4 + r;
                y[(size_t)(b * T_SEQ + q) * N_EMB + h * 64 + n * 16 + l16] =
                    (f16)(Oacc[m][n][r] * lPV[r]);
            }
        }
    }
}

// ---------------------------------------------------------------- launch
extern "C" void kernel_launch(void* const* d_in, const int* in_sizes, int n_in,
                              void* d_out, int out_size, void* d_ws, size_t ws_size,
                              hipStream_t stream) {
    const float* x      = (const float*)d_in[0];
    const float* ln1_g  = (const float*)d_in[1];
    const float* ln1_b  = (const float*)d_in[2];
    const float* w_attn = (const float*)d_in[3];
    const float* b_attn = (const float*)d_in[4];
    const float* w_proj = (const float*)d_in[5];
    const float* b_proj = (const float*)d_in[6];
    const float* ln2_g  = (const float*)d_in[7];
    const float* ln2_b  = (const float*)d_in[8];
    const float* w_fc   = (const float*)d_in[9];
    const float* b_fc   = (const float*)d_in[10];
    const float* w_fc2  = (const float*)d_in[11];
    const float* b_fc2  = (const float*)d_in[12];
    float* out = (float*)d_out;

    const size_t MB = 1024 * 1024;
    char* ws = (char*)d_ws;
    f16*   lnbuf = (f16*)ws;                        // 16 MB
    f16*   qkbuf = (f16*)(ws + 16 * MB);            // 32 MB: [M][2048] Q|K
    f16*   vTbuf = (f16*)(ws + 48 * MB);            // 16 MB: [b][h][d][t]
    f16*   ybuf  = (f16*)(ws + 64 * MB);            // 16 MB
    f16*   h     = (f16*)(ws + 80 * MB);            // 64 MB
    f16*   wT    = (f16*)(ws + 144 * MB);           // 26 MB
    f16* wT_attn = wT;
    f16* wT_proj = wT_attn + (size_t)3072 * 1024;
    f16* wT_fc   = wT_proj + (size_t)1024 * 1024;
    f16* wT_fc2  = wT_fc   + (size_t)1024 * 4096;

    wconv_kernel<<<dim3(3072 / 32, 1024 / 32), 256, 0, stream>>>(w_attn, wT_attn, 1024, 3072);
    wconv_kernel<<<dim3(1024 / 32, 1024 / 32), 256, 0, stream>>>(w_proj, wT_proj, 1024, 1024);
    wconv_kernel<<<dim3(4096 / 32, 1024 / 32), 256, 0, stream>>>(w_fc,   wT_fc,   1024, 4096);
    wconv_kernel<<<dim3(1024 / 32, 4096 / 32), 256, 0, stream>>>(w_fc2,  wT_fc2,  4096, 1024);

    ln_kernel<<<M_ROWS, 256, 0, stream>>>(x, ln1_g, ln1_b, lnbuf);
    gemm_f16<3><<<dim3(3072 / 128, M_ROWS / 128), 256, 0, stream>>>(
        lnbuf, wT_attn, b_attn, nullptr, nullptr, qkbuf, vTbuf, 1024, 3072);
    flash_kernel<<<dim3(16, 64), 256, 0, stream>>>(qkbuf, vTbuf, ybuf);
    gemm_f16<1><<<dim3(1024 / 128, M_ROWS / 128), 256, 0, stream>>>(
        ybuf, wT_proj, b_proj, x, out, nullptr, nullptr, 1024, 1024);
    ln_kernel<<<M_ROWS, 256, 0, stream>>>(out, ln2_g, ln2_b, lnbuf);
    gemm_f16_big<2><<<dim3(4096 / 128, M_ROWS / 256), 512, 0, stream>>>(
        lnbuf, wT_fc, b_fc, nullptr, nullptr, h, 1024, 4096);
    gemm_f16_big<1><<<dim3(1024 / 128, M_ROWS / 256), 512, 0, stream>>>(
        h, wT_fc2, b_fc2, out, out, nullptr, 4096, 1024);
}